// Round 1
// 176.662 us; speedup vs baseline: 1.0487x; 1.0487x over previous
//
#include <hip/hip_runtime.h>
#include <math.h>

#define B_N 8
#define IN_N 8
#define J_N 8
#define S_N 187
#define F_N 64
#define O_N 64
#define C_N 67
#define KS_N 15
#define SF_N (S_N * F_N)   // 11968
#define E_N 256
#define ROWS_N (B_N * J_N * S_N)  // 11968
#define SQRT_SF 0.85467470f  // sqrt(187/256)

#define NT_SPL 47           // 256-wide idx tiles covering SF_N
#define NCOMB 376           // combined blocks in k_mid2 (47*8)
#define NKTQT 2992          // ktqt blocks in k_mid2 (11968/4)
#define NRAW 576            // raw blocks in k_gemm (3*3*64)
#define NXPR 768            // xprime blocks in k_gemm (12*64)
#define NMAXP 256           // maxabs partial blocks

typedef __attribute__((ext_vector_type(8))) _Float16 half8;
typedef __attribute__((ext_vector_type(4))) _Float16 half4;
typedef __attribute__((ext_vector_type(4))) float floatx4;

// ---------------- wave helpers (wave = 64) ----------------
__device__ __forceinline__ float wave_sum(float v) {
#pragma unroll
  for (int off = 32; off > 0; off >>= 1) v += __shfl_down(v, off, 64);
  return __shfl(v, 0, 64);
}
__device__ __forceinline__ float wave_max(float v) {
#pragma unroll
  for (int off = 32; off > 0; off >>= 1) v = fmaxf(v, __shfl_down(v, off, 64));
  return __shfl(v, 0, 64);
}
__device__ __forceinline__ float lane_bc(float v, int l) {
  return __int_as_float(__builtin_amdgcn_readlane(__float_as_int(v), l));
}
__device__ __forceinline__ float bspline(float d) {
  float t2 = fmaxf(2.f - d, 0.f);
  float t1 = fmaxf(1.f - d, 0.f);
  return t2 * t2 * t2 * (1.f / 6.f) - t1 * t1 * t1 * (4.f / 6.f);
}
__device__ __forceinline__ float get_inv095(const float* __restrict__ maxp) {
  int lane = threadIdx.x & 63;
  float m = 0.f;
#pragma unroll
  for (int k = 0; k < NMAXP / 64; k++) m = fmaxf(m, maxp[lane + k * 64]);
  return 0.95f / (wave_max(m) + 1e-8f);
}

// ---------------- D1. global max |x| -> per-block maxima ----------------
__global__ void k_maxabs(const float4* __restrict__ x, float* __restrict__ maxp, int n4) {
  __shared__ float red[4];
  int tid = blockIdx.x * 256 + threadIdx.x;
  float m = 0.f;
  for (int i = tid; i < n4; i += gridDim.x * 256) {
    float4 v = x[i];
    m = fmaxf(m, fmaxf(fmaxf(fabsf(v.x), fabsf(v.y)), fmaxf(fabsf(v.z), fabsf(v.w))));
  }
  m = wave_max(m);
  if ((threadIdx.x & 63) == 0) red[threadIdx.x >> 6] = m;
  __syncthreads();
  if (threadIdx.x == 0)
    maxp[blockIdx.x] = fmaxf(fmaxf(red[0], red[1]), fmaxf(red[2], red[3]));
}

// ---------------- D2. spline ONCE: act[bi][j][idx] + energy partials ----
// One thread = one (b,i,idx) element; no i-loop -> short dependency chain,
// 3008 blocks -> full occupancy. Replaces BOTH k_energy's and old k_mid's
// spline passes (spline was evaluated 2x before; k_energy additionally ran
// at 1 block/CU with zero latency hiding).
__global__ void k_spline(const float* __restrict__ x_in, const float* __restrict__ sw,
                         const float* __restrict__ omiga, const float* __restrict__ maxp,
                         float* __restrict__ act, float* __restrict__ esum_p) {
  int tile = blockIdx.x, bi = blockIdx.y;
  int i = bi & 7;
  __shared__ float wl[J_N * C_N];   // [j][c] layout: random-c reads spread banks
  __shared__ float aom[J_N];
  __shared__ float red[4 * J_N];
  for (int t = threadIdx.x; t < J_N * C_N; t += 256) wl[t] = sw[i * J_N * C_N + t];
  if (threadIdx.x < J_N) aom[threadIdx.x] = fabsf(omiga[i * J_N + threadIdx.x]);
  int lane = threadIdx.x & 63, wid = threadIdx.x >> 6;
  float inv = get_inv095(maxp);
  __syncthreads();
  int idx = tile * 256 + threadIdx.x;
  float e[J_N] = {0, 0, 0, 0, 0, 0, 0, 0};
  if (idx < SF_N) {
    float x = x_in[(long)bi * SF_N + idx];
    float xn = fminf(fmaxf(x * inv, -0.99f), 0.99f);
    float u = (xn + 1.f) * 33.f;
    int c0 = (int)floorf(u) - 1;
    float sm[J_N] = {0, 0, 0, 0, 0, 0, 0, 0};
#pragma unroll
    for (int kk = 0; kk < 4; kk++) {
      int c = c0 + kk;
      if (c >= 0 && c < C_N) {
        float bas = bspline(fabsf(u - (float)c));
#pragma unroll
        for (int j = 0; j < J_N; j++) sm[j] += bas * wl[j * C_N + c];
      }
    }
#pragma unroll
    for (int j = 0; j < J_N; j++) {
      float a = sm[j] + aom[j] * x;
      act[((long)(bi * 8 + j)) * SF_N + idx] = a;
      e[j] = a * a;
    }
  }
#pragma unroll
  for (int j = 0; j < J_N; j++) {
    float v = e[j];
#pragma unroll
    for (int off = 32; off > 0; off >>= 1) v += __shfl_down(v, off, 64);
    if (lane == 0) red[wid * J_N + j] = v;
  }
  __syncthreads();
  if (threadIdx.x < J_N)
    esum_p[(long)(bi * 8 + threadIdx.x) * 48 + tile] =
        red[threadIdx.x] + red[8 + threadIdx.x] + red[16 + threadIdx.x] + red[24 + threadIdx.x];
}

// ---------------- D3. fold energy partials -> gate values (512) ---------
__global__ void k_reduceE(const float* __restrict__ esum_p, const float* __restrict__ tau,
                          const float* __restrict__ temp, float* __restrict__ g_mask,
                          float* __restrict__ g_g) {
  int t = blockIdx.x * 256 + threadIdx.x;  // t = (b*8+i)*8+j, 512 total
  if (t >= 512) return;
  int i = (t >> 3) & 7, j = t & 7;
  const float* p = esum_p + (long)t * 48;
  float s = 0.f;
#pragma unroll
  for (int k = 0; k < NT_SPL; k++) s += p[k];
  float E = s * (1.f / (float)SF_N);
  float sE = sqrtf(E + 1e-8f);
  float ta = fabsf(tau[i * 8 + j]);
  float tv = fabsf(temp[0]) * SQRT_SF + 1e-4f;
  float mask = 1.f / (1.f + expf(-(sE - ta) / tv));
  g_mask[t] = mask;
  g_g[t] = (sE / (ta + 1e-8f)) * mask;
}

// ---------------- D4. mid2 = combined-from-act U ktqt -------------------
__global__ void k_mid2(const float* __restrict__ act, const float* __restrict__ g_mask,
                       const float* __restrict__ g_g, const float* __restrict__ proj,
                       float* __restrict__ comb,
                       _Float16* __restrict__ khi, _Float16* __restrict__ klo,
                       _Float16* __restrict__ qhi, _Float16* __restrict__ qlo) {
  __shared__ float mk[64];
  int lane = threadIdx.x & 63;
  if (blockIdx.x < NCOMB) {
    // ---- combined: pure masked streaming sum over act (BW-bound) ----
    int b = blockIdx.x / 47, tile = blockIdx.x - b * 47;
    if (threadIdx.x < 64) mk[threadIdx.x] = g_mask[b * 64 + threadIdx.x];
    __syncthreads();
    int idx = tile * 256 + threadIdx.x;
    if (idx < SF_N) {
      float cb[J_N] = {0, 0, 0, 0, 0, 0, 0, 0};
#pragma unroll
      for (int i = 0; i < IN_N; i++) {
#pragma unroll
        for (int j = 0; j < J_N; j++)
          cb[j] += mk[i * 8 + j] * act[((long)((b * 8 + i) * 8 + j)) * SF_N + idx];
      }
#pragma unroll
      for (int j = 0; j < J_N; j++) comb[(b * J_N + j) * SF_N + idx] = cb[j];
    }
  } else {
    // ---- ktqt: one wave per (b,j,s) row; gates precomputed ----
    int w = threadIdx.x >> 6;
    int gr = (blockIdx.x - NCOMB) * 4 + w;  // 0..11967
    int bj = gr / S_N, s = gr - bj * S_N;
    int b = bj >> 3, j = bj & 7;
    int ig = lane >> 4;           // i-group 0..3
    int f4 = (lane & 15) * 4;     // f base
    int iK = b * 8 + 2 * ig;
    int iQ = iK + 1;
    float gK = g_g[iK * 8 + j];
    float gQ = g_g[iQ * 8 + j];
    float4 kr = *(const float4*)(proj + ((long)iK * S_N + s) * 64 + f4);
    float4 qr = *(const float4*)(proj + ((long)iQ * S_N + s) * 64 + f4);
    float kv[4] = {kr.x * gK, kr.y * gK, kr.z * gK, kr.w * gK};
    float qv[4] = {qr.x * gQ, qr.y * gQ, qr.z * gQ, qr.w * gQ};
    float mkv = wave_sum(kv[0] + kv[1] + kv[2] + kv[3]) * (1.f / 256.f);
    float mqv = wave_sum(qv[0] + qv[1] + qv[2] + qv[3]) * (1.f / 256.f);
    float vk = 0.f, vq = 0.f;
#pragma unroll
    for (int q = 0; q < 4; q++) {
      float dk = kv[q] - mkv; vk += dk * dk;
      float dq = qv[q] - mqv; vq += dq * dq;
    }
    vk = wave_sum(vk) * (1.f / 256.f);
    vq = wave_sum(vq) * (1.f / 256.f);
    float ik = 1.f / sqrtf(vk + 1e-5f);
    float iq = 1.f / sqrtf(vq + 1e-5f);
    long base = (long)gr * E_N + lane * 4;
    half4 hk4, lk4, hq4, lq4;
#pragma unroll
    for (int q = 0; q < 4; q++) {
      float fk = (kv[q] - mkv) * ik;
      float fq = (qv[q] - mqv) * iq;
      _Float16 hk = (_Float16)fk;
      _Float16 hq = (_Float16)fq;
      hk4[q] = hk; lk4[q] = (_Float16)(fk - (float)hk);
      hq4[q] = hq; lq4[q] = (_Float16)(fq - (float)hq);
    }
    *(half4*)(khi + base) = hk4;
    *(half4*)(klo + base) = lk4;
    *(half4*)(qhi + base) = hq4;
    *(half4*)(qlo + base) = lq4;
  }
}

// ---------------- D5. gemm = raw (MFMA) U xprime ----------------
__global__ void k_gemm(const _Float16* __restrict__ khi, const _Float16* __restrict__ klo,
                       const _Float16* __restrict__ qhi, const _Float16* __restrict__ qlo,
                       const float* __restrict__ temp, float* __restrict__ w1,
                       const float* __restrict__ comb, const float* __restrict__ W2,
                       const float* __restrict__ bparam, const float* __restrict__ lns,
                       const float* __restrict__ lnb, float* __restrict__ xprime) {
  __shared__ float smem[64 * 64 + 128];
  int lane = threadIdx.x & 63;
  if (blockIdx.x < NRAW) {
    // ---- raw: idx = st + 3*tt + 9*bj ----
    int idx = blockIdx.x;
    int st = idx % 3, tt = (idx / 3) % 3, bj = idx / 9;
    int wave = threadIdx.x >> 6;
    int quad = lane >> 4, m16 = lane & 15;
    int ebase = quad * 8;
    int mrow = st * 64 + wave * 16 + m16;
    if (mrow > S_N - 1) mrow = S_N - 1;
    long aoff = ((long)bj * S_N + mrow) * E_N + ebase;
    const _Float16* ah_p = khi + aoff;
    const _Float16* al_p = klo + aoff;
    const _Float16* bh_p[4];
    const _Float16* bl_p[4];
#pragma unroll
    for (int n = 0; n < 4; n++) {
      int t = tt * 64 + n * 16 + m16;
      if (t > S_N - 1) t = S_N - 1;
      long boff = ((long)bj * S_N + t) * E_N + ebase;
      bh_p[n] = qhi + boff;
      bl_p[n] = qlo + boff;
    }
    floatx4 acc[4] = {};
    for (int ec = 0; ec < 8; ec++) {
      half8 ah = *(const half8*)(ah_p + ec * 32);
      half8 al = *(const half8*)(al_p + ec * 32);
#pragma unroll
      for (int n = 0; n < 4; n++) {
        half8 bh = *(const half8*)(bh_p[n] + ec * 32);
        half8 bl = *(const half8*)(bl_p[n] + ec * 32);
        acc[n] = __builtin_amdgcn_mfma_f32_16x16x32_f16(ah, bh, acc[n], 0, 0, 0);
        acc[n] = __builtin_amdgcn_mfma_f32_16x16x32_f16(al, bh, acc[n], 0, 0, 0);
        acc[n] = __builtin_amdgcn_mfma_f32_16x16x32_f16(ah, bl, acc[n], 0, 0, 0);
      }
    }
    float tv = fabsf(temp[0]) * SQRT_SF + 1e-4f;
    float scale = 1.f / (16.f * tv);
#pragma unroll
    for (int n = 0; n < 4; n++) {
      int t = tt * 64 + n * 16 + m16;  // D col = lane&15
      if (t >= S_N) continue;
#pragma unroll
      for (int r = 0; r < 4; r++) {
        int s = st * 64 + wave * 16 + quad * 4 + r;  // D row = quad*4+reg
        if (s < S_N) w1[((long)bj * S_N + s) * S_N + t] = acc[n][r] * scale;
      }
    }
  } else {
    // ---- xprime: q = blk-576: tile = q%12, bj = q/12 ----
    int q = blockIdx.x - NRAW;
    int tile = q % 12, bj = q / 12;
    int j = bj & 7;
    float* w2s = smem;
    float* lss = smem + 4096;
    float* lbs = smem + 4160;
    const float4* wg = (const float4*)(W2 + j * 4096);
    float4* ws4 = (float4*)w2s;
    for (int idx = threadIdx.x; idx < 1024; idx += 256) ws4[idx] = wg[idx];
    if (threadIdx.x < 64) {
      lss[threadIdx.x] = lns[j * 64 + threadIdx.x];
      lbs[threadIdx.x] = lnb[j * 64 + threadIdx.x];
    }
    __syncthreads();
    int w = threadIdx.x >> 6;
    int sbase = tile * 16 + w * 4;
    float xln[4], acc[4];
#pragma unroll
    for (int rr = 0; rr < 4; rr++) {
      int s = sbase + rr;
      int sc = (s < S_N) ? s : S_N - 1;
      float x = comb[((long)bj * S_N + sc) * 64 + lane];
      float m = wave_sum(x) * (1.f / 64.f);
      float d = x - m;
      float var = wave_sum(d * d) * (1.f / 64.f);
      xln[rr] = d / sqrtf(var + 1e-5f) * lss[lane] + lbs[lane];
      acc[rr] = bparam[(j * S_N + sc) * 64 + lane];
    }
#pragma unroll
    for (int h = 0; h < 64; h++) {
      float w2v = w2s[h * 64 + lane];
#pragma unroll
      for (int rr = 0; rr < 4; rr++) acc[rr] += lane_bc(xln[rr], h) * w2v;
    }
#pragma unroll
    for (int rr = 0; rr < 4; rr++) {
      int s = sbase + rr;
      if (s < S_N) xprime[((long)bj * S_N + s) * 64 + lane] = acc[rr];
    }
  }
}

// ---------------- D6. final: softmax + attn apply + conv + residuals ----
__global__ void k_final(const float* __restrict__ xprime, const float* __restrict__ w1,
                        const float* __restrict__ comb, const float* __restrict__ w3,
                        const float* __restrict__ alpha, const float* __restrict__ beta,
                        const float* __restrict__ theta, const float* __restrict__ gamma,
                        float* __restrict__ out) {
  int tile = blockIdx.x, bj = blockIdx.y;
  int j = bj & 7;
  __shared__ float w1t[16 * 188];    // 12032 B total LDS
  int s0 = tile * 16;
  for (int idx = threadIdx.x; idx < 16 * S_N; idx += 256) {
    int r = idx / S_N, t = idx - r * S_N;
    int srow = s0 + r;
    w1t[r * 188 + t] = (srow < S_N) ? w1[((long)bj * S_N + srow) * S_N + t] : 0.f;
  }
  __syncthreads();
  int w = threadIdx.x >> 6, o = threadIdx.x & 63;
  // in-LDS row softmax on this wave's 4 rows (consumed only by wave w)
#pragma unroll
  for (int rr = 0; rr < 4; rr++) {
    float* row = &w1t[(w * 4 + rr) * 188];
    float v[3];
    float m = -1e30f;
#pragma unroll
    for (int q = 0; q < 3; q++) {
      int t = o + q * 64;
      v[q] = (t < S_N) ? row[t] : -1e30f;
      m = fmaxf(m, v[q]);
    }
    m = wave_max(m);
    float ssum = 0.f;
#pragma unroll
    for (int q = 0; q < 3; q++) {
      int t = o + q * 64;
      float e = (t < S_N) ? expf(v[q] - m) : 0.f;
      v[q] = e;
      ssum += e;
    }
    ssum = wave_sum(ssum);
    float invs = 1.f / ssum;
#pragma unroll
    for (int q = 0; q < 3; q++) {
      int t = o + q * 64;
      if (t < S_N) row[t] = v[q] * invs;
    }
  }
  // conv taps straight from global (L1-resident: same j across the block)
  float w3c[KS_N];
#pragma unroll
  for (int k = 0; k < KS_N; k++) w3c[k] = w3[j * 64 * KS_N + o * KS_N + k];
  const float* xpg = xprime + (long)bj * (S_N * 64);
  float aa = fabsf(alpha[j]), ba = fabsf(beta[j]), ta = fabsf(theta[j]), gv = gamma[j];
  float acc[4] = {0.f, 0.f, 0.f, 0.f};
  for (int t = 0; t < 184; t += 4) {
    float x0 = xpg[t * 64 + o];
    float x1 = xpg[(t + 1) * 64 + o];
    float x2 = xpg[(t + 2) * 64 + o];
    float x3 = xpg[(t + 3) * 64 + o];
#pragma unroll
    for (int rr = 0; rr < 4; rr++) {
      float4 wv = *(const float4*)&w1t[(w * 4 + rr) * 188 + t];
      acc[rr] += wv.x * x0 + wv.y * x1 + wv.z * x2 + wv.w * x3;
    }
  }
#pragma unroll
  for (int t = 184; t < S_N; t++) {
    float xv = xpg[t * 64 + o];
#pragma unroll
    for (int rr = 0; rr < 4; rr++) acc[rr] += w1t[(w * 4 + rr) * 188 + t] * xv;
  }
#pragma unroll
  for (int rr = 0; rr < 4; rr++) {
    int s = s0 + w * 4 + rr;
    if (s >= S_N) continue;
    float conv = 0.f;
#pragma unroll
    for (int k = 0; k < KS_N; k++) {
      int si = s + k - 7;
      if (si >= 0 && si < S_N) conv += xpg[si * 64 + o] * w3c[k];
    }
    float res = ba * acc[rr] + aa * xpg[s * 64 + o] + ta * conv +
                gv * comb[((long)bj * S_N + s) * 64 + o];
    out[((long)bj * S_N + s) * 64 + o] = res;
  }
}

extern "C" void kernel_launch(void* const* d_in, const int* in_sizes, int n_in,
                              void* d_out, int out_size, void* d_ws, size_t ws_size,
                              hipStream_t stream) {
  const float* x_in   = (const float*)d_in[0];
  const float* proj   = (const float*)d_in[1];
  const float* sw     = (const float*)d_in[2];
  const float* tau    = (const float*)d_in[3];
  const float* temp   = (const float*)d_in[4];
  const float* omiga  = (const float*)d_in[5];
  const float* W2     = (const float*)d_in[6];
  const float* bparam = (const float*)d_in[7];
  const float* lns    = (const float*)d_in[8];
  const float* lnb    = (const float*)d_in[9];
  const float* alpha  = (const float*)d_in[10];
  const float* beta   = (const float*)d_in[11];
  const float* theta  = (const float*)d_in[12];
  const float* gamma  = (const float*)d_in[13];
  const float* w3     = (const float*)d_in[14];

  float* out = (float*)d_out;
  float* xprime = out + B_N * J_N * S_N * O_N;  // second output, written directly

  float* wsf = (float*)d_ws;
  float* maxp   = wsf;                            // 256 floats (all written by D1)
  float* esum_p = wsf + 512;                      // 512*48 floats (partials, D2)
  float* g_mask = wsf + 512 + 512 * 48;           // 512 floats (D3)
  float* g_g    = g_mask + 512;                   // 512 floats (D3)
  float* act    = g_g + 512;                      // 64*8*SF_N floats = 24.5 MB (D2)
  const long RE = (long)ROWS_N * E_N;             // 3,063,808 halves per array
  _Float16* khi = (_Float16*)(act + (long)64 * 8 * SF_N);
  _Float16* klo = khi + RE;
  _Float16* qhi = klo + RE;
  _Float16* qlo = qhi + RE;
  float* w1   = (float*)khi + 2 * RE;             // 4 half arrays = 2*RE floats
  float* comb = w1 + (long)B_N * J_N * S_N * S_N;

  k_maxabs<<<NMAXP, 256, 0, stream>>>((const float4*)x_in, maxp, (B_N * IN_N * S_N * F_N) / 4);
  k_spline<<<dim3(NT_SPL, 64), 256, 0, stream>>>(x_in, sw, omiga, maxp, act, esum_p);
  k_reduceE<<<2, 256, 0, stream>>>(esum_p, tau, temp, g_mask, g_g);
  k_mid2<<<NCOMB + NKTQT, 256, 0, stream>>>(act, g_mask, g_g, proj, comb,
                                            khi, klo, qhi, qlo);
  k_gemm<<<NRAW + NXPR, 256, 0, stream>>>(khi, klo, qhi, qlo, temp, w1,
                                          comb, W2, bparam, lns, lnb, xprime);
  k_final<<<dim3(12, 64), 256, 0, stream>>>(xprime, w1, comb, w3, alpha, beta, theta, gamma, out);
}

// Round 2
// 165.294 us; speedup vs baseline: 1.1208x; 1.0688x over previous
//
#include <hip/hip_runtime.h>
#include <math.h>

#define B_N 8
#define IN_N 8
#define J_N 8
#define S_N 187
#define F_N 64
#define O_N 64
#define C_N 67
#define KS_N 15
#define SF_N (S_N * F_N)   // 11968
#define SF4_N (SF_N / 4)   // 2992 float4s per (b,i) plane
#define E_N 256
#define SQRT_SF 0.85467470f  // sqrt(187/256)

#define NT_SPL 12           // 1024-wide idx tiles (256 float4/block) covering SF_N
#define NCOMB 96            // combined blocks in k_mid2 (12*8)
#define NKTQT 2992          // ktqt blocks in k_mid2 (11968 rows / 4 waves)
#define NZERO 16            // fragment tail-zero blocks in k_mid2
#define NRAW 576            // raw blocks in k_gemm (3*3*64)
#define NXPR 768            // xprime blocks in k_gemm (12*64)
#define NMAXP 256           // maxabs partial blocks
#define FRAG_BJ 49152       // 12 tiles * 8 ec * 512 halves per bj

typedef __attribute__((ext_vector_type(8))) _Float16 half8;
typedef __attribute__((ext_vector_type(4))) _Float16 half4;
typedef __attribute__((ext_vector_type(4))) float floatx4;

// ---------------- wave helpers (wave = 64) ----------------
__device__ __forceinline__ float wave_sum(float v) {
#pragma unroll
  for (int off = 32; off > 0; off >>= 1) v += __shfl_down(v, off, 64);
  return __shfl(v, 0, 64);
}
__device__ __forceinline__ float wave_max(float v) {
#pragma unroll
  for (int off = 32; off > 0; off >>= 1) v = fmaxf(v, __shfl_down(v, off, 64));
  return __shfl(v, 0, 64);
}
__device__ __forceinline__ float lane_bc(float v, int l) {
  return __int_as_float(__builtin_amdgcn_readlane(__float_as_int(v), l));
}
__device__ __forceinline__ float bspline(float d) {
  float t2 = fmaxf(2.f - d, 0.f);
  float t1 = fmaxf(1.f - d, 0.f);
  return t2 * t2 * t2 * (1.f / 6.f) - t1 * t1 * t1 * (4.f / 6.f);
}
__device__ __forceinline__ float get_inv095(const float* __restrict__ maxp) {
  int lane = threadIdx.x & 63;
  float m = 0.f;
#pragma unroll
  for (int k = 0; k < NMAXP / 64; k++) m = fmaxf(m, maxp[lane + k * 64]);
  return 0.95f / (wave_max(m) + 1e-8f);
}
// gate = (sqrtE/tau) * sigmoid((sqrtE-tau)/tv), recomputed inline from the
// 12 per-tile energy partials (k_reduceE kernel removed: ~70 ops, L2-hit).
__device__ __forceinline__ float gate_g(const float* __restrict__ esum_p, int bi, int j,
                                        const float* __restrict__ tau, float tv) {
  const float* p = esum_p + ((long)bi * 8 + j) * NT_SPL;
  float s = 0.f;
#pragma unroll
  for (int k = 0; k < NT_SPL; k++) s += p[k];
  float sE = sqrtf(s * (1.f / (float)SF_N) + 1e-8f);
  float ta = fabsf(tau[(bi & 7) * 8 + j]);
  return (sE / (ta + 1e-8f)) / (1.f + expf(-(sE - ta) / tv));
}

// ---------------- D1. global max |x| -> per-block maxima ----------------
__global__ void k_maxabs(const float4* __restrict__ x, float* __restrict__ maxp, int n4) {
  __shared__ float red[4];
  int tid = blockIdx.x * 256 + threadIdx.x;
  float m = 0.f;
  for (int i = tid; i < n4; i += gridDim.x * 256) {
    float4 v = x[i];
    m = fmaxf(m, fmaxf(fmaxf(fabsf(v.x), fabsf(v.y)), fmaxf(fabsf(v.z), fabsf(v.w))));
  }
  m = wave_max(m);
  if ((threadIdx.x & 63) == 0) red[threadIdx.x >> 6] = m;
  __syncthreads();
  if (threadIdx.x == 0)
    maxp[blockIdx.x] = fmaxf(fmaxf(red[0], red[1]), fmaxf(red[2], red[3]));
}

// ---------------- D2. spline ONCE (float4-vectorized) -------------------
// One thread = one float4 of (b,i) x-plane; writes act + 12 energy partials
// per (bi,j). 16B/lane loads & stores (G13 coalescing sweet spot).
__global__ void k_spline(const float4* __restrict__ x4, const float* __restrict__ sw,
                         const float* __restrict__ omiga, const float* __restrict__ maxp,
                         float4* __restrict__ act4, float* __restrict__ esum_p) {
  int tile = blockIdx.x, bi = blockIdx.y;
  int i = bi & 7;
  __shared__ float wl[J_N * C_N];
  __shared__ float aom[J_N];
  __shared__ float red[4 * J_N];
  for (int t = threadIdx.x; t < J_N * C_N; t += 256) wl[t] = sw[i * J_N * C_N + t];
  if (threadIdx.x < J_N) aom[threadIdx.x] = fabsf(omiga[i * J_N + threadIdx.x]);
  int lane = threadIdx.x & 63, wid = threadIdx.x >> 6;
  float inv = get_inv095(maxp);
  __syncthreads();
  int i4 = tile * 256 + threadIdx.x;
  float e[J_N] = {0, 0, 0, 0, 0, 0, 0, 0};
  if (i4 < SF4_N) {
    float4 xv = x4[(long)bi * SF4_N + i4];
    float xs[4] = {xv.x, xv.y, xv.z, xv.w};
    float4 av[J_N];
#pragma unroll
    for (int c = 0; c < 4; c++) {
      float x = xs[c];
      float xn = fminf(fmaxf(x * inv, -0.99f), 0.99f);
      float u = (xn + 1.f) * 33.f;
      int c0 = (int)floorf(u) - 1;
      float sm[J_N] = {0, 0, 0, 0, 0, 0, 0, 0};
#pragma unroll
      for (int kk = 0; kk < 4; kk++) {
        int cc = c0 + kk;
        if (cc >= 0 && cc < C_N) {
          float bas = bspline(fabsf(u - (float)cc));
#pragma unroll
          for (int j = 0; j < J_N; j++) sm[j] += bas * wl[j * C_N + cc];
        }
      }
#pragma unroll
      for (int j = 0; j < J_N; j++) {
        float a = sm[j] + aom[j] * x;
        (&av[j].x)[c] = a;
        e[j] += a * a;
      }
    }
#pragma unroll
    for (int j = 0; j < J_N; j++) act4[((long)(bi * 8 + j)) * SF4_N + i4] = av[j];
  }
#pragma unroll
  for (int j = 0; j < J_N; j++) {
    float v = e[j];
#pragma unroll
    for (int off = 32; off > 0; off >>= 1) v += __shfl_down(v, off, 64);
    if (lane == 0) red[wid * J_N + j] = v;
  }
  __syncthreads();
  if (threadIdx.x < J_N)
    esum_p[((long)bi * 8 + threadIdx.x) * NT_SPL + tile] =
        red[threadIdx.x] + red[8 + threadIdx.x] + red[16 + threadIdx.x] + red[24 + threadIdx.x];
}

// ---------------- D3. mid2 = combined U ktqt U frag-tail-zero -----------
// ktqt writes K/Q in MFMA-FRAGMENT layout [bj][tile16][ec][lane][8 halves]
// so k_gemm's operand loads are fully coalesced (was: 16-way row gather,
// 16 cache-line requests per load instruction).
__global__ void k_mid2(const float4* __restrict__ act4, const float* __restrict__ esum_p,
                       const float* __restrict__ tau, const float* __restrict__ temp,
                       const float* __restrict__ proj, float4* __restrict__ comb4,
                       _Float16* __restrict__ khi, _Float16* __restrict__ klo,
                       _Float16* __restrict__ qhi, _Float16* __restrict__ qlo) {
  __shared__ float mk[64];
  int lane = threadIdx.x & 63;
  if (blockIdx.x < NCOMB) {
    // ---- combined: float4 masked streaming sum over act ----
    int b = blockIdx.x / NT_SPL, tile = blockIdx.x - b * NT_SPL;
    if (threadIdx.x < 64) {
      int i = threadIdx.x >> 3, j = threadIdx.x & 7;
      const float* p = esum_p + ((long)(b * 8 + i) * 8 + j) * NT_SPL;
      float s = 0.f;
#pragma unroll
      for (int k = 0; k < NT_SPL; k++) s += p[k];
      float sE = sqrtf(s * (1.f / (float)SF_N) + 1e-8f);
      float ta = fabsf(tau[i * 8 + j]);
      float tv = fabsf(temp[0]) * SQRT_SF + 1e-4f;
      mk[threadIdx.x] = 1.f / (1.f + expf(-(sE - ta) / tv));
    }
    __syncthreads();
    int i4 = tile * 256 + threadIdx.x;
    if (i4 < SF4_N) {
      float4 cb[J_N] = {};
#pragma unroll
      for (int i = 0; i < IN_N; i++) {
#pragma unroll
        for (int j = 0; j < J_N; j++) {
          float4 a = act4[((long)((b * 8 + i) * 8 + j)) * SF4_N + i4];
          float g = mk[i * 8 + j];
          cb[j].x += g * a.x; cb[j].y += g * a.y;
          cb[j].z += g * a.z; cb[j].w += g * a.w;
        }
      }
#pragma unroll
      for (int j = 0; j < J_N; j++) comb4[((long)(b * J_N + j)) * SF4_N + i4] = cb[j];
    }
  } else if (blockIdx.x < NCOMB + NKTQT) {
    // ---- ktqt: one wave per (b,j,s) row; gates inline; fragment store ----
    int w = threadIdx.x >> 6;
    int gr = (blockIdx.x - NCOMB) * 4 + w;  // 0..11967
    int bj = gr / S_N, s = gr - bj * S_N;
    int b = bj >> 3, j = bj & 7;
    int ig = lane >> 4;           // i-group 0..3
    int f4 = (lane & 15) * 4;     // f base
    int iK = b * 8 + 2 * ig;
    int iQ = iK + 1;
    float tv = fabsf(temp[0]) * SQRT_SF + 1e-4f;
    float gK = gate_g(esum_p, iK, j, tau, tv);
    float gQ = gate_g(esum_p, iQ, j, tau, tv);
    float4 kr = *(const float4*)(proj + ((long)iK * S_N + s) * 64 + f4);
    float4 qr = *(const float4*)(proj + ((long)iQ * S_N + s) * 64 + f4);
    float kv[4] = {kr.x * gK, kr.y * gK, kr.z * gK, kr.w * gK};
    float qv[4] = {qr.x * gQ, qr.y * gQ, qr.z * gQ, qr.w * gQ};
    float mkv = wave_sum(kv[0] + kv[1] + kv[2] + kv[3]) * (1.f / 256.f);
    float mqv = wave_sum(qv[0] + qv[1] + qv[2] + qv[3]) * (1.f / 256.f);
    float vk = 0.f, vq = 0.f;
#pragma unroll
    for (int q = 0; q < 4; q++) {
      float dk = kv[q] - mkv; vk += dk * dk;
      float dq = qv[q] - mqv; vq += dq * dq;
    }
    vk = wave_sum(vk) * (1.f / 256.f);
    vq = wave_sum(vq) * (1.f / 256.f);
    float ik = 1.f / sqrtf(vk + 1e-5f);
    float iq = 1.f / sqrtf(vq + 1e-5f);
    half4 hk4, lk4, hq4, lq4;
#pragma unroll
    for (int q = 0; q < 4; q++) {
      float fk = (kv[q] - mkv) * ik;
      float fq = (qv[q] - mqv) * iq;
      _Float16 hk = (_Float16)fk;
      _Float16 hq = (_Float16)fq;
      hk4[q] = hk; lk4[q] = (_Float16)(fk - (float)hk);
      hq4[q] = hq; lq4[q] = (_Float16)(fq - (float)hq);
    }
    // fragment layout: lane holds e = lane*4+q -> ec=lane>>3, quad=(lane>>1)&3,
    // pos=(lane&1)*4+q; slot byte order matches consumer's lane*8 half8 read.
    int stile = s >> 4, m16 = s & 15;
    long fo = ((long)bj * 12 + stile) * 4096 + (lane >> 3) * 512 +
              (((lane >> 1) & 3) * 16 + m16) * 8 + (lane & 1) * 4;
    *(half4*)(khi + fo) = hk4;
    *(half4*)(klo + fo) = lk4;
    *(half4*)(qhi + fo) = hq4;
    *(half4*)(qlo + fo) = lq4;
  } else {
    // ---- zero fragment tail slots (tile 11, m16 11..15) so k_gemm needs
    // no clamping/masking (workspace is poisoned, not zeroed) ----
    int zb = blockIdx.x - (NCOMB + NKTQT);
    float4 z = {0.f, 0.f, 0.f, 0.f};
    for (int t = zb * 256 + threadIdx.x; t < 10240; t += NZERO * 256) {
      int bj = t / 160, r = t - bj * 160;
      int ec = r / 20, rr = r - ec * 20;
      int quad = rr / 5, m16 = 11 + rr - quad * 5;
      long fo = ((long)bj * 12 + 11) * 4096 + ec * 512 + (quad * 16 + m16) * 8;
      *(float4*)(khi + fo) = z;
      *(float4*)(klo + fo) = z;
      *(float4*)(qhi + fo) = z;
      *(float4*)(qlo + fo) = z;
    }
  }
}

// ---------------- D4. gemm = raw (MFMA, coalesced frags) U xprime -------
__global__ void k_gemm(const _Float16* __restrict__ khi, const _Float16* __restrict__ klo,
                       const _Float16* __restrict__ qhi, const _Float16* __restrict__ qlo,
                       const float* __restrict__ temp, float* __restrict__ w1,
                       const float* __restrict__ comb, const float* __restrict__ W2,
                       const float* __restrict__ bparam, const float* __restrict__ lns,
                       const float* __restrict__ lnb, float* __restrict__ xprime) {
  __shared__ float smem[64 * 64 + 128];
  int lane = threadIdx.x & 63;
  if (blockIdx.x < NRAW) {
    // ---- raw: idx = st + 3*tt + 9*bj; operands read in fragment order ----
    int idx = blockIdx.x;
    int st = idx % 3, tt = (idx / 3) % 3, bj = idx / 9;
    int wave = threadIdx.x >> 6;
    int quad = lane >> 4, m16 = lane & 15;
    long fb = (long)bj * FRAG_BJ + lane * 8;
    const _Float16* ah_p = khi + fb + (st * 4 + wave) * 4096;
    const _Float16* al_p = klo + fb + (st * 4 + wave) * 4096;
    const _Float16* bh_p = qhi + fb + tt * 4 * 4096;
    const _Float16* bl_p = qlo + fb + tt * 4 * 4096;
    floatx4 acc[4] = {};
    for (int ec = 0; ec < 8; ec++) {
      half8 ah = *(const half8*)(ah_p + ec * 512);
      half8 al = *(const half8*)(al_p + ec * 512);
#pragma unroll
      for (int n = 0; n < 4; n++) {
        half8 bh = *(const half8*)(bh_p + n * 4096 + ec * 512);
        half8 bl = *(const half8*)(bl_p + n * 4096 + ec * 512);
        acc[n] = __builtin_amdgcn_mfma_f32_16x16x32_f16(ah, bh, acc[n], 0, 0, 0);
        acc[n] = __builtin_amdgcn_mfma_f32_16x16x32_f16(al, bh, acc[n], 0, 0, 0);
        acc[n] = __builtin_amdgcn_mfma_f32_16x16x32_f16(ah, bl, acc[n], 0, 0, 0);
      }
    }
    float tv = fabsf(temp[0]) * SQRT_SF + 1e-4f;
    float scale = 1.f / (16.f * tv);
#pragma unroll
    for (int n = 0; n < 4; n++) {
      int t = tt * 64 + n * 16 + m16;  // D col = lane&15
      if (t >= S_N) continue;
#pragma unroll
      for (int r = 0; r < 4; r++) {
        int s = st * 64 + wave * 16 + quad * 4 + r;  // D row = quad*4+reg
        if (s < S_N) w1[((long)bj * S_N + s) * S_N + t] = acc[n][r] * scale;
      }
    }
  } else {
    // ---- xprime: q = blk-576: tile = q%12, bj = q/12 ----
    int q = blockIdx.x - NRAW;
    int tile = q % 12, bj = q / 12;
    int j = bj & 7;
    float* w2s = smem;
    float* lss = smem + 4096;
    float* lbs = smem + 4160;
    const float4* wg = (const float4*)(W2 + j * 4096);
    float4* ws4 = (float4*)w2s;
    for (int idx = threadIdx.x; idx < 1024; idx += 256) ws4[idx] = wg[idx];
    if (threadIdx.x < 64) {
      lss[threadIdx.x] = lns[j * 64 + threadIdx.x];
      lbs[threadIdx.x] = lnb[j * 64 + threadIdx.x];
    }
    __syncthreads();
    int w = threadIdx.x >> 6;
    int sbase = tile * 16 + w * 4;
    float xln[4], acc[4];
#pragma unroll
    for (int rr = 0; rr < 4; rr++) {
      int s = sbase + rr;
      int sc = (s < S_N) ? s : S_N - 1;
      float x = comb[((long)bj * S_N + sc) * 64 + lane];
      float m = wave_sum(x) * (1.f / 64.f);
      float d = x - m;
      float var = wave_sum(d * d) * (1.f / 64.f);
      xln[rr] = d / sqrtf(var + 1e-5f) * lss[lane] + lbs[lane];
      acc[rr] = bparam[(j * S_N + sc) * 64 + lane];
    }
#pragma unroll
    for (int h = 0; h < 64; h++) {
      float w2v = w2s[h * 64 + lane];
#pragma unroll
      for (int rr = 0; rr < 4; rr++) acc[rr] += lane_bc(xln[rr], h) * w2v;
    }
#pragma unroll
    for (int rr = 0; rr < 4; rr++) {
      int s = sbase + rr;
      if (s < S_N) xprime[((long)bj * S_N + s) * 64 + lane] = acc[rr];
    }
  }
}

// ---------------- D5. final: softmax + attn apply + conv + residuals ----
__global__ void k_final(const float* __restrict__ xprime, const float* __restrict__ w1,
                        const float* __restrict__ comb, const float* __restrict__ w3,
                        const float* __restrict__ alpha, const float* __restrict__ beta,
                        const float* __restrict__ theta, const float* __restrict__ gamma,
                        float* __restrict__ out) {
  int tile = blockIdx.x, bj = blockIdx.y;
  int j = bj & 7;
  __shared__ float w1t[16 * 188];    // 12032 B total LDS
  int s0 = tile * 16;
  for (int idx = threadIdx.x; idx < 16 * S_N; idx += 256) {
    int r = idx / S_N, t = idx - r * S_N;
    int srow = s0 + r;
    w1t[r * 188 + t] = (srow < S_N) ? w1[((long)bj * S_N + srow) * S_N + t] : 0.f;
  }
  __syncthreads();
  int w = threadIdx.x >> 6, o = threadIdx.x & 63;
  // in-LDS row softmax on this wave's 4 rows (consumed only by wave w)
#pragma unroll
  for (int rr = 0; rr < 4; rr++) {
    float* row = &w1t[(w * 4 + rr) * 188];
    float v[3];
    float m = -1e30f;
#pragma unroll
    for (int q = 0; q < 3; q++) {
      int t = o + q * 64;
      v[q] = (t < S_N) ? row[t] : -1e30f;
      m = fmaxf(m, v[q]);
    }
    m = wave_max(m);
    float ssum = 0.f;
#pragma unroll
    for (int q = 0; q < 3; q++) {
      int t = o + q * 64;
      float e = (t < S_N) ? expf(v[q] - m) : 0.f;
      v[q] = e;
      ssum += e;
    }
    ssum = wave_sum(ssum);
    float invs = 1.f / ssum;
#pragma unroll
    for (int q = 0; q < 3; q++) {
      int t = o + q * 64;
      if (t < S_N) row[t] = v[q] * invs;
    }
  }
  // conv taps straight from global (L1-resident: same j across the block)
  float w3c[KS_N];
#pragma unroll
  for (int k = 0; k < KS_N; k++) w3c[k] = w3[j * 64 * KS_N + o * KS_N + k];
  const float* xpg = xprime + (long)bj * (S_N * 64);
  float aa = fabsf(alpha[j]), ba = fabsf(beta[j]), ta = fabsf(theta[j]), gv = gamma[j];
  float acc[4] = {0.f, 0.f, 0.f, 0.f};
  for (int t = 0; t < 184; t += 4) {
    float x0 = xpg[t * 64 + o];
    float x1 = xpg[(t + 1) * 64 + o];
    float x2 = xpg[(t + 2) * 64 + o];
    float x3 = xpg[(t + 3) * 64 + o];
#pragma unroll
    for (int rr = 0; rr < 4; rr++) {
      float4 wv = *(const float4*)&w1t[(w * 4 + rr) * 188 + t];
      acc[rr] += wv.x * x0 + wv.y * x1 + wv.z * x2 + wv.w * x3;
    }
  }
#pragma unroll
  for (int t = 184; t < S_N; t++) {
    float xv = xpg[t * 64 + o];
#pragma unroll
    for (int rr = 0; rr < 4; rr++) acc[rr] += w1t[(w * 4 + rr) * 188 + t] * xv;
  }
#pragma unroll
  for (int rr = 0; rr < 4; rr++) {
    int s = s0 + w * 4 + rr;
    if (s >= S_N) continue;
    float conv = 0.f;
#pragma unroll
    for (int k = 0; k < KS_N; k++) {
      int si = s + k - 7;
      if (si >= 0 && si < S_N) conv += xpg[si * 64 + o] * w3c[k];
    }
    float res = ba * acc[rr] + aa * xpg[s * 64 + o] + ta * conv +
                gv * comb[((long)bj * S_N + s) * 64 + o];
    out[((long)bj * S_N + s) * 64 + o] = res;
  }
}

extern "C" void kernel_launch(void* const* d_in, const int* in_sizes, int n_in,
                              void* d_out, int out_size, void* d_ws, size_t ws_size,
                              hipStream_t stream) {
  const float* x_in   = (const float*)d_in[0];
  const float* proj   = (const float*)d_in[1];
  const float* sw     = (const float*)d_in[2];
  const float* tau    = (const float*)d_in[3];
  const float* temp   = (const float*)d_in[4];
  const float* omiga  = (const float*)d_in[5];
  const float* W2     = (const float*)d_in[6];
  const float* bparam = (const float*)d_in[7];
  const float* lns    = (const float*)d_in[8];
  const float* lnb    = (const float*)d_in[9];
  const float* alpha  = (const float*)d_in[10];
  const float* beta   = (const float*)d_in[11];
  const float* theta  = (const float*)d_in[12];
  const float* gamma  = (const float*)d_in[13];
  const float* w3     = (const float*)d_in[14];

  float* out = (float*)d_out;
  float* xprime = out + B_N * J_N * S_N * O_N;  // second output, written directly

  float* wsf = (float*)d_ws;
  float* maxp   = wsf;                            // 256 floats (all written by D1)
  float* esum_p = wsf + 512;                      // 512*12 floats (partials, D2)
  float* act    = wsf + 512 + 512 * NT_SPL;       // 64*8*SF_N floats = 24.5 MB
  const long FR = (long)64 * FRAG_BJ;             // 3,145,728 halves per frag array
  _Float16* khi = (_Float16*)(act + (long)64 * 8 * SF_N);
  _Float16* klo = khi + FR;
  _Float16* qhi = klo + FR;
  _Float16* qlo = qhi + FR;
  float* w1   = (float*)(qlo + FR);
  float* comb = w1 + (long)B_N * J_N * S_N * S_N;

  k_maxabs<<<NMAXP, 256, 0, stream>>>((const float4*)x_in, maxp, (B_N * IN_N * S_N * F_N) / 4);
  k_spline<<<dim3(NT_SPL, 64), 256, 0, stream>>>((const float4*)x_in, sw, omiga, maxp,
                                                 (float4*)act, esum_p);
  k_mid2<<<NCOMB + NKTQT + NZERO, 256, 0, stream>>>((const float4*)act, esum_p, tau, temp,
                                                    proj, (float4*)comb, khi, klo, qhi, qlo);
  k_gemm<<<NRAW + NXPR, 256, 0, stream>>>(khi, klo, qhi, qlo, temp, w1,
                                          comb, W2, bparam, lns, lnb, xprime);
  k_final<<<dim3(12, 64), 256, 0, stream>>>(xprime, w1, comb, w3, alpha, beta, theta, gamma, out);
}